// Round 1
// baseline (377.773 us; speedup 1.0000x reference)
//
#include <hip/hip_runtime.h>
#include <math.h>

typedef __attribute__((ext_vector_type(8))) short bf16x8;
typedef __attribute__((ext_vector_type(4))) float f32x4;
typedef unsigned short u16;
typedef unsigned int u32;

#define DEVFN static __device__ __forceinline__

constexpr int NB  = 32;      // batch
constexpr int DLn = 290;     // drug length
constexpr int PLc = 1000;    // protein length
constexpr int MD  = NB * DLn;   // 9280  (= 145*64)
constexpr int MP  = NB * PLc;   // 32000 (= 500*64)

DEVFN u16 f2b(float f) {                      // fp32 -> bf16 RNE
    u32 u = __builtin_bit_cast(u32, f);
    u32 r = u + 0x7fffu + ((u >> 16) & 1u);
    return (u16)(r >> 16);
}
DEVFN float b2f(u16 s) { return __builtin_bit_cast(float, (u32)s << 16); }
DEVFN float sigm(float x) { return 1.0f / (1.0f + __expf(-x)); }

// ---------------- PE table: pe[p][c], p<1000 ----------------
__global__ void pe_kernel(float* __restrict__ pe) {
    int p = blockIdx.x, c = threadIdx.x;
    float div = __expf((float)(c & ~1) * (-9.210340371976184f / 256.0f)); // ln(1e4)
    float ang = (float)p * div;
    pe[p * 256 + c] = (c & 1) ? cosf(ang) : sinf(ang);
}

// ---------------- e = x + scale*pe  (bf16) ----------------
__global__ void eadd_kernel(const float* __restrict__ drug, const float* __restrict__ prot,
                            const float* __restrict__ scale_d, const float* __restrict__ scale_p,
                            const float* __restrict__ pe,
                            u16* __restrict__ e_d, u16* __restrict__ e_p) {
    int r = blockIdx.x, c = threadIdx.x;
    if (r < MD) {
        int i = r % DLn;
        e_d[(size_t)r * 256 + c] = f2b(drug[(size_t)r * 256 + c] + scale_d[0] * pe[i * 256 + c]);
    } else {
        int rr = r - MD;
        int j = rr % PLc;
        e_p[(size_t)rr * 256 + c] = f2b(prot[(size_t)rr * 256 + c] + scale_p[0] * pe[j * 256 + c]);
    }
}

// ---------------- weights: convert + transpose to WT[n][k] bf16 ----------------
struct WPtrs { const float* w[10]; };
__global__ void wprep_kernel(WPtrs wp, u16* __restrict__ wt) {
    int m = blockIdx.x >> 8, n = blockIdx.x & 255, k = threadIdx.x;
    wt[((size_t)m << 16) + n * 256 + k] = f2b(wp.w[m][k * 256 + n]);
}

// ---------------- generic bf16 GEMM: C[M,256] = A[M,256] @ WT^T + bias ----------------
struct GCfg { const u16* A; const u16* BT; const float* bias; u16* C; int mtiles; int sig; };
struct GCfg8 { GCfg c[8]; };

__global__ __launch_bounds__(256) void gemm_kernel(GCfg8 cfgs) {
    const GCfg cfg = cfgs.c[blockIdx.z];
    const int mt = blockIdx.x;
    if (mt >= cfg.mtiles) return;
    const int nt = blockIdx.y;
    __shared__ u16 As[64 * 56];
    __shared__ u16 Bs[64 * 56];
    const int tid = threadIdx.x;
    const int lane = tid & 63, w = tid >> 6, ln = lane & 15, g = lane >> 4;
    const int lr = tid >> 2, lc = tid & 3;
    const u16* Ag = cfg.A + (size_t)(mt * 64 + lr) * 256 + lc * 8;
    const u16* Bg = cfg.BT + (size_t)(nt * 64 + lr) * 256 + lc * 8;
    const int m0 = (w >> 1) * 32, n0 = (w & 1) * 32;
    f32x4 acc[2][2] = {};
    for (int k0 = 0; k0 < 256; k0 += 32) {
        uint4 av = *(const uint4*)(Ag + k0);
        uint4 bv = *(const uint4*)(Bg + k0);
        __syncthreads();
        *(uint4*)&As[lr * 56 + lc * 8] = av;
        *(uint4*)&Bs[lr * 56 + lc * 8] = bv;
        __syncthreads();
        #pragma unroll
        for (int mi = 0; mi < 2; mi++) {
            bf16x8 af = *(const bf16x8*)&As[(m0 + mi * 16 + ln) * 56 + g * 8];
            #pragma unroll
            for (int ni = 0; ni < 2; ni++) {
                bf16x8 bfv = *(const bf16x8*)&Bs[(n0 + ni * 16 + ln) * 56 + g * 8];
                acc[mi][ni] = __builtin_amdgcn_mfma_f32_16x16x32_bf16(af, bfv, acc[mi][ni], 0, 0, 0);
            }
        }
    }
    #pragma unroll
    for (int mi = 0; mi < 2; mi++) {
        #pragma unroll
        for (int ni = 0; ni < 2; ni++) {
            const int n = nt * 64 + n0 + ni * 16 + ln;
            const float bb = cfg.bias[n];
            const int rowb = mt * 64 + m0 + mi * 16 + g * 4;
            #pragma unroll
            for (int r = 0; r < 4; r++) {
                float v = acc[mi][ni][r] + bb;
                if (cfg.sig) v = sigm(v);
                cfg.C[(size_t)(rowb + r) * 256 + n] = f2b(v);
            }
        }
    }
}

// ---------------- attention: one block per (b,h) ----------------
constexpr int JT = 32;        // j-tile
constexpr int NJT = 32;       // covers j 0..1023 (mask >=1000)
constexpr int IR = 320;       // padded drug rows
constexpr int QS_S = 72, P_S = 56, PT_S = 328, VDT_S = 328, KS_S = 72, VPT_S = 48;

__global__ __launch_bounds__(512) void attn_kernel(
        const u16* __restrict__ Qd, const u16* __restrict__ Kd, const u16* __restrict__ Vd,
        const u16* __restrict__ Kp, const u16* __restrict__ Vp, const u16* __restrict__ Qp,
        const float* __restrict__ alpha,
        u16* __restrict__ ctx_d, u16* __restrict__ ctx_p, float* __restrict__ cm) {
    __shared__ u16 Qs[IR * QS_S];     // Q' = [sa*Qd ; sb*Kd], [320][64] (+pad)
    __shared__ u16 Pm[IR * P_S];      // P row-major [320][32]
    __shared__ u16 PTm[JT * PT_S];    // P^T [32][320]
    __shared__ u16 VdT[32 * VDT_S];   // Vd^T [32][320]
    __shared__ u16 Ks[JT * KS_S];     // K' = [Kp ; Qp] tile [32][64]
    __shared__ u16 VpT[32 * VPT_S];   // Vp^T tile [32][32]
    __shared__ float m_l[IR];
    __shared__ float l_l[IR];
    __shared__ float colpart[8 * JT];

    const int bh = blockIdx.x, b = bh >> 3, h = bh & 7;
    const int tid = threadIdx.x;
    const int w = tid >> 6, lane = tid & 63, ln = lane & 15, g = lane >> 4;

    const float a = sigm(alpha[0]);
    const float inv = 0.1767766952966369f;     // 1/sqrt(32)
    const float sa = a * inv, sb = (1.0f - a) * inv;

    const int mts[3] = { w, w + 8, (w < 4) ? (w + 16) : -1 };

    const size_t rbd = (size_t)b * DLn * 256 + h * 32;
    const size_t rbp = (size_t)b * PLc * 256 + h * 32;

    // ---- load Q' (scaled), zero-pad rows ----
    for (int c = tid; c < DLn * 8; c += 512) {
        int i = c >> 3, ch = c & 7, half = ch >> 2, part = ch & 3;
        const u16* src = (half ? Kd : Qd) + rbd + (size_t)i * 256 + part * 8;
        float s = half ? sb : sa;
        uint4 v = *(const uint4*)src;
        u16 e[8]; *(uint4*)e = v;
        u16 o[8];
        #pragma unroll
        for (int t = 0; t < 8; t++) o[t] = f2b(b2f(e[t]) * s);
        *(uint4*)&Qs[i * QS_S + ch * 8] = *(uint4*)o;
    }
    for (int c = tid; c < (IR - DLn) * 8; c += 512) {
        int i = DLn + (c >> 3), ch = c & 7;
        *(uint4*)&Qs[i * QS_S + ch * 8] = make_uint4(0, 0, 0, 0);
    }
    // ---- Vd^T, zero-pad cols ----
    for (int c = tid; c < IR * 32; c += 512) {
        int i = c >> 5, d = c & 31;
        VdT[d * VDT_S + i] = (i < DLn) ? Vd[rbd + (size_t)i * 256 + d] : (u16)0;
    }
    for (int i = tid; i < IR; i += 512) { m_l[i] = -1e30f; l_l[i] = 0.0f; }
    __syncthreads();

    // ---- pass 1: online row max / sum ----
    for (int jt = 0; jt < NJT; jt++) {
        const int j0 = jt * JT;
        if (tid < 256) {
            int jj = tid >> 3, ch = tid & 7, half = ch >> 2, part = ch & 3;
            int j = j0 + jj;
            uint4 v = make_uint4(0, 0, 0, 0);
            if (j < PLc) v = *(const uint4*)((half ? Qp : Kp) + rbp + (size_t)j * 256 + part * 8);
            *(uint4*)&Ks[jj * KS_S + ch * 8] = v;
        }
        __syncthreads();
        #pragma unroll
        for (int ti = 0; ti < 3; ti++) {
            const int mt = mts[ti];
            if (mt < 0) continue;
            f32x4 acc0 = {0,0,0,0}, acc1 = {0,0,0,0};
            #pragma unroll
            for (int ks = 0; ks < 2; ks++) {
                bf16x8 af = *(const bf16x8*)&Qs[(mt * 16 + ln) * QS_S + ks * 32 + g * 8];
                bf16x8 b0 = *(const bf16x8*)&Ks[ln * KS_S + ks * 32 + g * 8];
                bf16x8 b1 = *(const bf16x8*)&Ks[(16 + ln) * KS_S + ks * 32 + g * 8];
                acc0 = __builtin_amdgcn_mfma_f32_16x16x32_bf16(af, b0, acc0, 0, 0, 0);
                acc1 = __builtin_amdgcn_mfma_f32_16x16x32_bf16(af, b1, acc1, 0, 0, 0);
            }
            if (j0 + ln >= PLc)      { acc0[0] = acc0[1] = acc0[2] = acc0[3] = -1e30f; }
            if (j0 + 16 + ln >= PLc) { acc1[0] = acc1[1] = acc1[2] = acc1[3] = -1e30f; }
            const int ib = mt * 16 + g * 4;
            #pragma unroll
            for (int r = 0; r < 4; r++) {
                float mx = fmaxf(acc0[r], acc1[r]);
                mx = fmaxf(mx, __shfl_xor(mx, 1));
                mx = fmaxf(mx, __shfl_xor(mx, 2));
                mx = fmaxf(mx, __shfl_xor(mx, 4));
                mx = fmaxf(mx, __shfl_xor(mx, 8));
                float mo = m_l[ib + r], lo = l_l[ib + r];
                float mn = fmaxf(mo, mx);
                float s = __expf(acc0[r] - mn) + __expf(acc1[r] - mn);
                s += __shfl_xor(s, 1);
                s += __shfl_xor(s, 2);
                s += __shfl_xor(s, 4);
                s += __shfl_xor(s, 8);
                if (ln == 0) { m_l[ib + r] = mn; l_l[ib + r] = lo * __expf(mo - mn) + s; }
            }
        }
        __syncthreads();
    }
    for (int i = tid; i < IR; i += 512) l_l[i] = 1.0f / l_l[i];   // now reciprocal
    __syncthreads();

    // ---- pass 2: P, ctx_d, ctx_p, column sums ----
    f32x4 accd[3][2] = {};
    for (int jt = 0; jt < NJT; jt++) {
        const int j0 = jt * JT;
        if (tid < 256) {
            int jj = tid >> 3, ch = tid & 7, half = ch >> 2, part = ch & 3;
            int j = j0 + jj;
            uint4 v = make_uint4(0, 0, 0, 0);
            if (j < PLc) v = *(const uint4*)((half ? Qp : Kp) + rbp + (size_t)j * 256 + part * 8);
            *(uint4*)&Ks[jj * KS_S + ch * 8] = v;
        }
        for (int c = tid; c < JT * 32; c += 512) {
            int jj = c >> 5, d = c & 31;
            int j = j0 + jj;
            VpT[d * VPT_S + jj] = (j < PLc) ? Vp[rbp + (size_t)j * 256 + d] : (u16)0;
        }
        __syncthreads();
        float cs0 = 0.0f, cs1 = 0.0f;
        #pragma unroll
        for (int ti = 0; ti < 3; ti++) {
            const int mt = mts[ti];
            if (mt < 0) continue;
            f32x4 acc0 = {0,0,0,0}, acc1 = {0,0,0,0};
            #pragma unroll
            for (int ks = 0; ks < 2; ks++) {
                bf16x8 af = *(const bf16x8*)&Qs[(mt * 16 + ln) * QS_S + ks * 32 + g * 8];
                bf16x8 b0 = *(const bf16x8*)&Ks[ln * KS_S + ks * 32 + g * 8];
                bf16x8 b1 = *(const bf16x8*)&Ks[(16 + ln) * KS_S + ks * 32 + g * 8];
                acc0 = __builtin_amdgcn_mfma_f32_16x16x32_bf16(af, b0, acc0, 0, 0, 0);
                acc1 = __builtin_amdgcn_mfma_f32_16x16x32_bf16(af, b1, acc1, 0, 0, 0);
            }
            const int ib = mt * 16 + g * 4;
            const bool vA = (j0 + ln) < PLc, vB = (j0 + 16 + ln) < PLc;
            u16 pb0[4], pb1[4];
            #pragma unroll
            for (int r = 0; r < 4; r++) {
                const int i = ib + r;
                const float mm = m_l[i], rl = l_l[i];
                float p0 = (vA && i < DLn) ? __expf(acc0[r] - mm) * rl : 0.0f;
                float p1 = (vB && i < DLn) ? __expf(acc1[r] - mm) * rl : 0.0f;
                cs0 += p0; cs1 += p1;
                pb0[r] = f2b(p0); pb1[r] = f2b(p1);
                Pm[i * P_S + ln] = pb0[r];
                Pm[i * P_S + 16 + ln] = pb1[r];
            }
            *(ushort4*)&PTm[ln * PT_S + mt * 16 + g * 4]        = make_ushort4(pb0[0], pb0[1], pb0[2], pb0[3]);
            *(ushort4*)&PTm[(16 + ln) * PT_S + mt * 16 + g * 4] = make_ushort4(pb1[0], pb1[1], pb1[2], pb1[3]);
        }
        cs0 += __shfl_xor(cs0, 16); cs0 += __shfl_xor(cs0, 32);
        cs1 += __shfl_xor(cs1, 16); cs1 += __shfl_xor(cs1, 32);
        if (g == 0) { colpart[w * JT + ln] = cs0; colpart[w * JT + 16 + ln] = cs1; }
        __syncthreads();
        // ctx_d += P @ Vp_tile
        #pragma unroll
        for (int ti = 0; ti < 3; ti++) {
            const int mt = mts[ti];
            if (mt < 0) continue;
            bf16x8 af = *(const bf16x8*)&Pm[(mt * 16 + ln) * P_S + g * 8];
            #pragma unroll
            for (int nd = 0; nd < 2; nd++) {
                bf16x8 bv = *(const bf16x8*)&VpT[(nd * 16 + ln) * VPT_S + g * 8];
                accd[ti][nd] = __builtin_amdgcn_mfma_f32_16x16x32_bf16(af, bv, accd[ti][nd], 0, 0, 0);
            }
        }
        // ctx_p tile = P^T @ Vd  (waves 0-3); colsum finalize (wave 4)
        if (w < 4) {
            const int jsub = w & 1, dsub = w >> 1;
            f32x4 ap = {0,0,0,0};
            #pragma unroll
            for (int k = 0; k < 10; k++) {
                bf16x8 af = *(const bf16x8*)&PTm[(jsub * 16 + ln) * PT_S + k * 32 + g * 8];
                bf16x8 bv = *(const bf16x8*)&VdT[(dsub * 16 + ln) * VDT_S + k * 32 + g * 8];
                ap = __builtin_amdgcn_mfma_f32_16x16x32_bf16(af, bv, ap, 0, 0, 0);
            }
            const int d = dsub * 16 + ln;
            const int jb = j0 + jsub * 16 + g * 4;
            #pragma unroll
            for (int r = 0; r < 4; r++) {
                if (jb + r < PLc) ctx_p[rbp + (size_t)(jb + r) * 256 + d] = f2b(ap[r]);
            }
        } else if (w == 4 && lane < JT) {
            float tot = 0.0f;
            #pragma unroll
            for (int ww = 0; ww < 8; ww++) tot += colpart[ww * JT + lane];
            if (j0 + lane < PLc) cm[(size_t)(b * PLc + j0 + lane) * 8 + h] = tot * (1.0f / 290.0f);
        }
        __syncthreads();
    }
    // ---- write ctx_d ----
    #pragma unroll
    for (int ti = 0; ti < 3; ti++) {
        const int mt = mts[ti];
        if (mt < 0) continue;
        #pragma unroll
        for (int nd = 0; nd < 2; nd++) {
            const int d = nd * 16 + ln;
            const int ib = mt * 16 + g * 4;
            #pragma unroll
            for (int r = 0; r < 4; r++) {
                if (ib + r < DLn) ctx_d[rbd + (size_t)(ib + r) * 256 + d] = f2b(accd[ti][nd][r]);
            }
        }
    }
}

// ---------------- final combine ----------------
__global__ void combine_kernel(const float* __restrict__ drug, const float* __restrict__ prot,
        const float* __restrict__ scale_d, const float* __restrict__ scale_p,
        const float* __restrict__ pe,
        const u16* __restrict__ Xd, const u16* __restrict__ Xp,
        const u16* __restrict__ gate_d, const u16* __restrict__ gate_p,
        const float* __restrict__ cm,
        const float* __restrict__ w_fc_dp, const float* __restrict__ b_fc_dp,
        const float* __restrict__ w_fc_pd, const float* __restrict__ b_fc_pd,
        float* __restrict__ out) {
    int r = blockIdx.x, c = threadIdx.x;
    if (r < MD) {
        int b = r / DLn, i = r % DLn;
        float e = drug[(size_t)r * 256 + c] + scale_d[0] * pe[i * 256 + c];
        float da = b_fc_dp[c];
        #pragma unroll
        for (int hh = 0; hh < 8; hh++) da += 0.001f * w_fc_dp[hh * 256 + c];
        float v = e + b2f(Xd[(size_t)r * 256 + c]) * b2f(gate_d[(size_t)r * 256 + c]) * sigm(da);
        out[((size_t)b * 1290 + i) * 256 + c] = v;
    } else {
        int rr = r - MD;
        int b = rr / PLc, j = rr % PLc;
        float e = prot[(size_t)rr * 256 + c] + scale_p[0] * pe[j * 256 + c];
        float pa = b_fc_pd[c];
        #pragma unroll
        for (int hh = 0; hh < 8; hh++) pa += cm[(size_t)rr * 8 + hh] * w_fc_pd[hh * 256 + c];
        float v = e + b2f(Xp[(size_t)rr * 256 + c]) * b2f(gate_p[(size_t)rr * 256 + c]) * sigm(pa);
        out[((size_t)b * 1290 + 290 + j) * 256 + c] = v;
    }
}

extern "C" void kernel_launch(void* const* d_in, const int* in_sizes, int n_in,
                              void* d_out, int out_size, void* d_ws, size_t ws_size,
                              hipStream_t stream) {
    (void)in_sizes; (void)n_in; (void)out_size;
    const float* drug    = (const float*)d_in[0];
    const float* prot    = (const float*)d_in[1];
    const float* scale_d = (const float*)d_in[2];
    const float* scale_p = (const float*)d_in[3];

    char* ws = (char*)d_ws;
    size_t off = 0;
    auto alloc = [&](size_t bytes) -> void* {
        void* p = ws + off;
        off += (bytes + 255) & ~(size_t)255;
        return p;
    };
    float* pe   = (float*)alloc((size_t)1000 * 256 * 4);
    u16* e_d    = (u16*)alloc((size_t)MD * 256 * 2);
    u16* e_p    = (u16*)alloc((size_t)MP * 256 * 2);
    u16* wt     = (u16*)alloc((size_t)10 * 65536 * 2);
    u16* Qd     = (u16*)alloc((size_t)MD * 256 * 2);
    u16* Kd     = (u16*)alloc((size_t)MD * 256 * 2);
    u16* Vd     = (u16*)alloc((size_t)MD * 256 * 2);
    u16* gate_d = (u16*)alloc((size_t)MD * 256 * 2);
    u16* Kp     = (u16*)alloc((size_t)MP * 256 * 2);
    u16* Vp     = (u16*)alloc((size_t)MP * 256 * 2);
    u16* Qp     = (u16*)alloc((size_t)MP * 256 * 2);
    u16* gate_p = (u16*)alloc((size_t)MP * 256 * 2);
    u16* ctxd   = (u16*)alloc((size_t)MD * 256 * 2);
    u16* ctxp   = (u16*)alloc((size_t)MP * 256 * 2);
    float* cm   = (float*)alloc((size_t)MP * 8 * 4);
    u16* Xd     = (u16*)alloc((size_t)MD * 256 * 2);
    u16* Xp     = (u16*)alloc((size_t)MP * 256 * 2);
    if (off > ws_size) return;   // insufficient workspace -> fail loudly

    pe_kernel<<<1000, 256, 0, stream>>>(pe);

    WPtrs wp;
    const int wsrc[10] = {4, 12, 14, 25, 6, 8, 10, 27, 16, 18};
    for (int m = 0; m < 10; m++) wp.w[m] = (const float*)d_in[wsrc[m]];
    wprep_kernel<<<2560, 256, 0, stream>>>(wp, wt);

    eadd_kernel<<<MD + MP, 256, 0, stream>>>(drug, prot, scale_d, scale_p, pe, e_d, e_p);

    auto W = [&](int slot) { return wt + (size_t)slot * 65536; };
    GCfg8 pc;
    pc.c[0] = { e_d, W(0), (const float*)d_in[5],  Qd,     145, 0 };
    pc.c[1] = { e_d, W(1), (const float*)d_in[13], Kd,     145, 0 };
    pc.c[2] = { e_d, W(2), (const float*)d_in[15], Vd,     145, 0 };
    pc.c[3] = { e_d, W(3), (const float*)d_in[26], gate_d, 145, 1 };
    pc.c[4] = { e_p, W(4), (const float*)d_in[7],  Kp,     500, 0 };
    pc.c[5] = { e_p, W(5), (const float*)d_in[9],  Vp,     500, 0 };
    pc.c[6] = { e_p, W(6), (const float*)d_in[11], Qp,     500, 0 };
    pc.c[7] = { e_p, W(7), (const float*)d_in[28], gate_p, 500, 1 };
    gemm_kernel<<<dim3(500, 4, 8), 256, 0, stream>>>(pc);

    attn_kernel<<<256, 512, 0, stream>>>(Qd, Kd, Vd, Kp, Vp, Qp,
                                         (const float*)d_in[20], ctxd, ctxp, cm);

    GCfg8 oc = pc;
    oc.c[0] = { ctxd, W(8), (const float*)d_in[17], Xd, 145, 0 };
    oc.c[1] = { ctxp, W(9), (const float*)d_in[19], Xp, 500, 0 };
    gemm_kernel<<<dim3(500, 4, 2), 256, 0, stream>>>(oc);

    combine_kernel<<<MD + MP, 256, 0, stream>>>(drug, prot, scale_d, scale_p, pe,
        Xd, Xp, gate_d, gate_p, cm,
        (const float*)d_in[21], (const float*)d_in[22],
        (const float*)d_in[23], (const float*)d_in[24],
        (float*)d_out);
}

// Round 2
// 216.238 us; speedup vs baseline: 1.7470x; 1.7470x over previous
//
#include <hip/hip_runtime.h>
#include <math.h>

typedef __attribute__((ext_vector_type(8))) short bf16x8;
typedef __attribute__((ext_vector_type(4))) float f32x4;
typedef unsigned short u16;
typedef unsigned int u32;

#define DEVFN static __device__ __forceinline__

constexpr int NB  = 32;
constexpr int DLn = 290;
constexpr int PLc = 1000;
constexpr int MD  = NB * DLn;   // 9280
constexpr int MP  = NB * PLc;   // 32000

DEVFN u16 f2b(float f) {
    u32 u = __builtin_bit_cast(u32, f);
    u32 r = u + 0x7fffu + ((u >> 16) & 1u);
    return (u16)(r >> 16);
}
DEVFN float b2f(u16 s) { return __builtin_bit_cast(float, (u32)s << 16); }
DEVFN float sigm(float x) { return 1.0f / (1.0f + __expf(-x)); }

// ---------------- PE table ----------------
__global__ void pe_kernel(float* __restrict__ pe) {
    int p = blockIdx.x, c = threadIdx.x;
    float div = __expf((float)(c & ~1) * (-9.210340371976184f / 256.0f));
    float ang = (float)p * div;
    pe[p * 256 + c] = (c & 1) ? cosf(ang) : sinf(ang);
}

// ---------------- e = x + scale*pe (bf16) ----------------
__global__ void eadd_kernel(const float* __restrict__ drug, const float* __restrict__ prot,
                            const float* __restrict__ scale_d, const float* __restrict__ scale_p,
                            const float* __restrict__ pe,
                            u16* __restrict__ e_d, u16* __restrict__ e_p) {
    int r = blockIdx.x, c = threadIdx.x;
    if (r < MD) {
        int i = r % DLn;
        e_d[(size_t)r * 256 + c] = f2b(drug[(size_t)r * 256 + c] + scale_d[0] * pe[i * 256 + c]);
    } else {
        int rr = r - MD;
        int j = rr % PLc;
        e_p[(size_t)rr * 256 + c] = f2b(prot[(size_t)rr * 256 + c] + scale_p[0] * pe[j * 256 + c]);
    }
}

// ---------------- weight prep: WT[n][k] bf16 ----------------
struct WPtrs { const float* w[10]; };
__global__ void wprep_kernel(WPtrs wp, u16* __restrict__ wt) {
    int m = blockIdx.x >> 8, n = blockIdx.x & 255, k = threadIdx.x;
    wt[((size_t)m << 16) + n * 256 + k] = f2b(wp.w[m][k * 256 + n]);
}

// ---------------- GEMM: C[M,256] = A[M,256] @ WT^T + bias, BK=256 one phase ----------------
struct GCfg { const u16* A; const u16* BT; const float* bias; u16* C; int mtiles; int sig; };
struct GCfg8 { GCfg c[8]; };

__global__ __launch_bounds__(256) void gemm_kernel(GCfg8 cfgs) {
    const GCfg cfg = cfgs.c[blockIdx.z];
    const int mt = blockIdx.x;
    if (mt >= cfg.mtiles) return;
    const int nt = blockIdx.y;
    __shared__ u16 As[64][264];
    __shared__ u16 Bs[64][264];
    const int tid = threadIdx.x;
    const int lane = tid & 63, w = tid >> 6, ln = lane & 15, g = lane >> 4;
    const int lr = tid >> 2, lc = tid & 3;
    const u16* Ag = cfg.A + (size_t)(mt * 64 + lr) * 256 + lc * 8;
    const u16* Bg = cfg.BT + (size_t)(nt * 64 + lr) * 256 + lc * 8;
    uint4 av[8], bv[8];
    #pragma unroll
    for (int kk = 0; kk < 8; kk++) {
        av[kk] = *(const uint4*)(Ag + kk * 32);
        bv[kk] = *(const uint4*)(Bg + kk * 32);
    }
    #pragma unroll
    for (int kk = 0; kk < 8; kk++) {
        *(uint4*)&As[lr][lc * 8 + kk * 32] = av[kk];
        *(uint4*)&Bs[lr][lc * 8 + kk * 32] = bv[kk];
    }
    __syncthreads();
    const int m0 = (w >> 1) * 32, n0 = (w & 1) * 32;
    f32x4 acc[2][2] = {};
    #pragma unroll
    for (int k0 = 0; k0 < 8; k0++) {
        #pragma unroll
        for (int mi = 0; mi < 2; mi++) {
            bf16x8 af = *(const bf16x8*)&As[m0 + mi * 16 + ln][k0 * 32 + g * 8];
            #pragma unroll
            for (int ni = 0; ni < 2; ni++) {
                bf16x8 bfv = *(const bf16x8*)&Bs[n0 + ni * 16 + ln][k0 * 32 + g * 8];
                acc[mi][ni] = __builtin_amdgcn_mfma_f32_16x16x32_bf16(af, bfv, acc[mi][ni], 0, 0, 0);
            }
        }
    }
    #pragma unroll
    for (int mi = 0; mi < 2; mi++) {
        #pragma unroll
        for (int ni = 0; ni < 2; ni++) {
            const int n = nt * 64 + n0 + ni * 16 + ln;
            const float bb = cfg.bias[n];
            const int rowb = mt * 64 + m0 + mi * 16 + g * 4;
            #pragma unroll
            for (int r = 0; r < 4; r++) {
                float v = acc[mi][ni][r] + bb;
                if (cfg.sig) v = sigm(v);
                cfg.C[(size_t)(rowb + r) * 256 + n] = f2b(v);
            }
        }
    }
}

// ---------------- attention: one block per (b,h), no-max softmax, 2 sweeps ----------------
__global__ __launch_bounds__(512) void attn_kernel(
        const u16* __restrict__ Qd, const u16* __restrict__ Kd, const u16* __restrict__ Vd,
        const u16* __restrict__ Kp, const u16* __restrict__ Vp, const u16* __restrict__ Qp,
        const float* __restrict__ alpha,
        u16* __restrict__ ctx_d, u16* __restrict__ ctx_p, float* __restrict__ cm) {
    __shared__ u16 Ks[2][64][72];                     // K' = [Kp;Qp] tiles, dbuf
    __shared__ union {
        struct { u16 VpT[2][32][72]; u16 Pm[320][72]; } s1;   // sweep1
        struct { u16 PT[64][328]; u16 VdT[32][328]; } s2;     // sweep2
    } U;
    __shared__ float r_l[320];
    __shared__ float colpart[8][64];

    const int bh = blockIdx.x, b = bh >> 3, h = bh & 7;
    const int tid = threadIdx.x;
    const int w = tid >> 6, lane = tid & 63, ln = lane & 15, g = lane >> 4;

    const float a = sigm(alpha[0]);
    const float inv = 0.1767766952966369f;
    const float sa = a * inv, sb = (1.0f - a) * inv;
    const int nmt = (w < 4) ? 3 : 2;
    const int mtsA[3] = { w, w + 8, w + 16 };

    const size_t rbd = (size_t)b * DLn * 256 + h * 32;
    const size_t rbp = (size_t)b * PLc * 256 + h * 32;

    // ---- Q' fragments in registers (scaled, masked) ----
    bf16x8 Qf[3][2];
    #pragma unroll
    for (int t = 0; t < 3; t++) {
        const int i = mtsA[t] * 16 + ln;
        #pragma unroll
        for (int ks = 0; ks < 2; ks++) {
            u16 o[8] = {0,0,0,0,0,0,0,0};
            if (t < nmt && i < DLn) {
                const u16* src = (ks ? Kd : Qd) + rbd + (size_t)i * 256 + g * 8;
                const float s = ks ? sb : sa;
                uint4 v = *(const uint4*)src;
                u16 e[8]; *(uint4*)e = v;
                #pragma unroll
                for (int q = 0; q < 8; q++) o[q] = f2b(b2f(e[q]) * s);
            }
            Qf[t][ks] = *(bf16x8*)o;
        }
    }

    // staging thread mappings
    const int s_jj = tid >> 3, s_ch = tid & 7;
    const u16* s_src = ((s_ch >> 2) ? Qp : Kp) + rbp + (s_ch & 3) * 8;
    const int v_j = tid & 63, v_d0 = (tid >> 6) * 4;

    // ---- prologue: stage tile 0 ----
    {
        int j = s_jj;   // j0 = 0
        uint4 kv = (j < PLc) ? *(const uint4*)(s_src + (size_t)j * 256) : make_uint4(0,0,0,0);
        uint2 vv = (v_j < PLc) ? *(const uint2*)(Vp + rbp + (size_t)v_j * 256 + v_d0) : make_uint2(0,0);
        *(uint4*)&Ks[0][s_jj][s_ch * 8] = kv;
        u16 e[4]; *(uint2*)e = vv;
        #pragma unroll
        for (int q = 0; q < 4; q++) U.s1.VpT[0][v_d0 + q][v_j] = e[q];
    }
    __syncthreads();

    // ---- sweep 1: S^T orientation -> rowsums + ctx_d~ ----
    float rs[3] = {0.f, 0.f, 0.f};
    f32x4 accd[3][2] = {};
    for (int jt = 0; jt < 16; jt++) {
        const int cur = jt & 1, j0 = jt * 64;
        // prefetch next tile (j>=1000 masked to zero; jt=15 stages zeros, harmless)
        const int jn = j0 + 64 + s_jj;
        uint4 kv = (jn < PLc) ? *(const uint4*)(s_src + (size_t)jn * 256) : make_uint4(0,0,0,0);
        const int vn = j0 + 64 + v_j;
        uint2 vv = (vn < PLc) ? *(const uint2*)(Vp + rbp + (size_t)vn * 256 + v_d0) : make_uint2(0,0);

        bf16x8 kf[4][2];
        #pragma unroll
        for (int js = 0; js < 4; js++)
            #pragma unroll
            for (int ks = 0; ks < 2; ks++)
                kf[js][ks] = *(const bf16x8*)&Ks[cur][js * 16 + ln][ks * 32 + g * 8];

        #pragma unroll
        for (int t = 0; t < 3; t++) {
            if (t >= nmt) break;
            const int mt = mtsA[t];
            f32x4 acc[4] = {};
            #pragma unroll
            for (int ks = 0; ks < 2; ks++)
                #pragma unroll
                for (int js = 0; js < 4; js++)
                    acc[js] = __builtin_amdgcn_mfma_f32_16x16x32_bf16(kf[js][ks], Qf[t][ks], acc[js], 0, 0, 0);
            const int irow = mt * 16 + ln;
            #pragma unroll
            for (int js = 0; js < 4; js++) {
                u16 pb[4];
                float psum = 0.f;
                #pragma unroll
                for (int r = 0; r < 4; r++) {
                    const int j = j0 + js * 16 + g * 4 + r;
                    float p = (j < PLc) ? __expf(acc[js][r]) : 0.0f;
                    psum += p;
                    pb[r] = f2b(p);
                }
                rs[t] += psum;
                *(ushort4*)&U.s1.Pm[irow][js * 16 + g * 4] = *(ushort4*)pb;
            }
        }
        // ctx_d accumulate (wave-local Pm rows; in-order LDS within wave)
        #pragma unroll
        for (int t = 0; t < 3; t++) {
            if (t >= nmt) break;
            const int mt = mtsA[t];
            #pragma unroll
            for (int ks2 = 0; ks2 < 2; ks2++) {
                bf16x8 af = *(const bf16x8*)&U.s1.Pm[mt * 16 + ln][ks2 * 32 + g * 8];
                #pragma unroll
                for (int nd = 0; nd < 2; nd++) {
                    bf16x8 bv = *(const bf16x8*)&U.s1.VpT[cur][nd * 16 + ln][ks2 * 32 + g * 8];
                    accd[t][nd] = __builtin_amdgcn_mfma_f32_16x16x32_bf16(af, bv, accd[t][nd], 0, 0, 0);
                }
            }
        }
        // write staged next tile
        *(uint4*)&Ks[cur ^ 1][s_jj][s_ch * 8] = kv;
        {
            u16 e[4]; *(uint2*)e = vv;
            #pragma unroll
            for (int q = 0; q < 4; q++) U.s1.VpT[cur ^ 1][v_d0 + q][v_j] = e[q];
        }
        __syncthreads();
    }

    // ---- row sums -> reciprocals ----
    #pragma unroll
    for (int t = 0; t < 3; t++) {
        float v = rs[t];
        v += __shfl_xor(v, 16);
        v += __shfl_xor(v, 32);
        rs[t] = v;
    }
    if (g == 0) {
        #pragma unroll
        for (int t = 0; t < 3; t++) {
            if (t >= nmt) break;
            const int i = mtsA[t] * 16 + ln;
            r_l[i] = (i < DLn) ? 1.0f / rs[t] : 0.0f;
        }
    }
    __syncthreads();

    // ---- ctx_d write (scaled), VdTn build, stage Ks tile0 ----
    #pragma unroll
    for (int t = 0; t < 3; t++) {
        if (t >= nmt) break;
        const int mt = mtsA[t];
        #pragma unroll
        for (int r = 0; r < 4; r++) {
            const int i = mt * 16 + g * 4 + r;
            if (i < DLn) {
                const float ri = r_l[i];
                #pragma unroll
                for (int nd = 0; nd < 2; nd++)
                    ctx_d[rbd + (size_t)i * 256 + nd * 16 + ln] = f2b(accd[t][nd][r] * ri);
            }
        }
    }
    for (int c = tid; c < 320 * 8; c += 512) {
        const int i = c >> 3, d0 = (c & 7) * 4;
        u16 o[4] = {0,0,0,0};
        if (i < DLn) {
            const float ri = r_l[i];
            uint2 v = *(const uint2*)(Vd + rbd + (size_t)i * 256 + d0);
            u16 e[4]; *(uint2*)e = v;
            #pragma unroll
            for (int q = 0; q < 4; q++) o[q] = f2b(b2f(e[q]) * ri);
        }
        #pragma unroll
        for (int q = 0; q < 4; q++) U.s2.VdT[d0 + q][i] = o[q];
    }
    {   // stage Ks tile 0 into buf 0 (safe: last Ks[0] read was jt=14, barriers since)
        int j = s_jj;
        uint4 kv = (j < PLc) ? *(const uint4*)(s_src + (size_t)j * 256) : make_uint4(0,0,0,0);
        *(uint4*)&Ks[0][s_jj][s_ch * 8] = kv;
    }
    // preload reciprocal regs for sweep2 (i = mt*16 + g*4 + r)
    float rr[3][4];
    #pragma unroll
    for (int t = 0; t < 3; t++)
        #pragma unroll
        for (int r = 0; r < 4; r++)
            rr[t][r] = (t < nmt) ? r_l[mtsA[t] * 16 + g * 4 + r] : 0.0f;
    __syncthreads();

    // ---- sweep 2: S orientation -> ctx_p + column means ----
    for (int jt = 0; jt < 16; jt++) {
        const int cur = jt & 1, j0 = jt * 64;
        const int jn = j0 + 64 + s_jj;
        uint4 kv = (jn < PLc) ? *(const uint4*)(s_src + (size_t)jn * 256) : make_uint4(0,0,0,0);

        bf16x8 kf[4][2];
        #pragma unroll
        for (int js = 0; js < 4; js++)
            #pragma unroll
            for (int ks = 0; ks < 2; ks++)
                kf[js][ks] = *(const bf16x8*)&Ks[cur][js * 16 + ln][ks * 32 + g * 8];

        float csl[4] = {0.f, 0.f, 0.f, 0.f};
        #pragma unroll
        for (int t = 0; t < 3; t++) {
            if (t >= nmt) break;
            const int mt = mtsA[t];
            f32x4 acc[4] = {};
            #pragma unroll
            for (int ks = 0; ks < 2; ks++)
                #pragma unroll
                for (int js = 0; js < 4; js++)
                    acc[js] = __builtin_amdgcn_mfma_f32_16x16x32_bf16(Qf[t][ks], kf[js][ks], acc[js], 0, 0, 0);
            #pragma unroll
            for (int js = 0; js < 4; js++) {
                const bool jok = (j0 + js * 16 + ln) < PLc;
                u16 pb[4];
                #pragma unroll
                for (int r = 0; r < 4; r++) {
                    float p = jok ? __expf(acc[js][r]) : 0.0f;
                    csl[js] += p * rr[t][r];
                    pb[r] = f2b(p);
                }
                *(ushort4*)&U.s2.PT[js * 16 + ln][mt * 16 + g * 4] = *(ushort4*)pb;
            }
        }
        #pragma unroll
        for (int js = 0; js < 4; js++) {
            float v = csl[js];
            v += __shfl_xor(v, 16);
            v += __shfl_xor(v, 32);
            csl[js] = v;
        }
        if (g == 0) {
            #pragma unroll
            for (int js = 0; js < 4; js++) colpart[w][js * 16 + ln] = csl[js];
        }
        *(uint4*)&Ks[cur ^ 1][s_jj][s_ch * 8] = kv;
        __syncthreads();

        // phase 2: ctx_p tile (all 8 waves) + cm (wave 0)
        {
            const int js2 = w & 3, ds2 = w >> 2;
            f32x4 ap = {};
            #pragma unroll
            for (int k = 0; k < 10; k++) {
                bf16x8 af = *(const bf16x8*)&U.s2.PT[js2 * 16 + ln][k * 32 + g * 8];
                bf16x8 bv = *(const bf16x8*)&U.s2.VdT[ds2 * 16 + ln][k * 32 + g * 8];
                ap = __builtin_amdgcn_mfma_f32_16x16x32_bf16(af, bv, ap, 0, 0, 0);
            }
            const int d = ds2 * 16 + ln;
            #pragma unroll
            for (int r = 0; r < 4; r++) {
                const int j = j0 + js2 * 16 + g * 4 + r;
                if (j < PLc) ctx_p[rbp + (size_t)j * 256 + d] = f2b(ap[r]);
            }
        }
        if (w == 0) {
            float tot = 0.f;
            #pragma unroll
            for (int ww = 0; ww < 8; ww++) tot += colpart[ww][lane];
            const int j = j0 + lane;
            if (j < PLc) cm[(size_t)(b * PLc + j) * 8 + h] = tot * (1.0f / 290.0f);
        }
        __syncthreads();
    }
}

// ---------------- final combine ----------------
__global__ void combine_kernel(const float* __restrict__ drug, const float* __restrict__ prot,
        const float* __restrict__ scale_d, const float* __restrict__ scale_p,
        const float* __restrict__ pe,
        const u16* __restrict__ Xd, const u16* __restrict__ Xp,
        const u16* __restrict__ gate_d, const u16* __restrict__ gate_p,
        const float* __restrict__ cm,
        const float* __restrict__ w_fc_dp, const float* __restrict__ b_fc_dp,
        const float* __restrict__ w_fc_pd, const float* __restrict__ b_fc_pd,
        float* __restrict__ out) {
    int r = blockIdx.x, c = threadIdx.x;
    if (r < MD) {
        int b = r / DLn, i = r % DLn;
        float e = drug[(size_t)r * 256 + c] + scale_d[0] * pe[i * 256 + c];
        float da = b_fc_dp[c];
        #pragma unroll
        for (int hh = 0; hh < 8; hh++) da += 0.001f * w_fc_dp[hh * 256 + c];
        float v = e + b2f(Xd[(size_t)r * 256 + c]) * b2f(gate_d[(size_t)r * 256 + c]) * sigm(da);
        out[((size_t)b * 1290 + i) * 256 + c] = v;
    } else {
        int rr = r - MD;
        int b = rr / PLc, j = rr % PLc;
        float e = prot[(size_t)rr * 256 + c] + scale_p[0] * pe[j * 256 + c];
        float pa = b_fc_pd[c];
        #pragma unroll
        for (int hh = 0; hh < 8; hh++) pa += cm[(size_t)rr * 8 + hh] * w_fc_pd[hh * 256 + c];
        float v = e + b2f(Xp[(size_t)rr * 256 + c]) * b2f(gate_p[(size_t)rr * 256 + c]) * sigm(pa);
        out[((size_t)b * 1290 + 290 + j) * 256 + c] = v;
    }
}

extern "C" void kernel_launch(void* const* d_in, const int* in_sizes, int n_in,
                              void* d_out, int out_size, void* d_ws, size_t ws_size,
                              hipStream_t stream) {
    (void)in_sizes; (void)n_in; (void)out_size;
    const float* drug    = (const float*)d_in[0];
    const float* prot    = (const float*)d_in[1];
    const float* scale_d = (const float*)d_in[2];
    const float* scale_p = (const float*)d_in[3];

    char* ws = (char*)d_ws;
    size_t off = 0;
    auto alloc = [&](size_t bytes) -> void* {
        void* p = ws + off;
        off += (bytes + 255) & ~(size_t)255;
        return p;
    };
    float* pe   = (float*)alloc((size_t)1000 * 256 * 4);
    u16* e_d    = (u16*)alloc((size_t)MD * 256 * 2);
    u16* e_p    = (u16*)alloc((size_t)MP * 256 * 2);
    u16* wt     = (u16*)alloc((size_t)10 * 65536 * 2);
    u16* Qd     = (u16*)alloc((size_t)MD * 256 * 2);
    u16* Kd     = (u16*)alloc((size_t)MD * 256 * 2);
    u16* Vd     = (u16*)alloc((size_t)MD * 256 * 2);
    u16* gate_d = (u16*)alloc((size_t)MD * 256 * 2);
    u16* Kp     = (u16*)alloc((size_t)MP * 256 * 2);
    u16* Vp     = (u16*)alloc((size_t)MP * 256 * 2);
    u16* Qp     = (u16*)alloc((size_t)MP * 256 * 2);
    u16* gate_p = (u16*)alloc((size_t)MP * 256 * 2);
    u16* ctxd   = (u16*)alloc((size_t)MD * 256 * 2);
    u16* ctxp   = (u16*)alloc((size_t)MP * 256 * 2);
    float* cm   = (float*)alloc((size_t)MP * 8 * 4);
    u16* Xd     = (u16*)alloc((size_t)MD * 256 * 2);
    u16* Xp     = (u16*)alloc((size_t)MP * 256 * 2);
    if (off > ws_size) return;

    pe_kernel<<<1000, 256, 0, stream>>>(pe);

    WPtrs wp;
    const int wsrc[10] = {4, 12, 14, 25, 6, 8, 10, 27, 16, 18};
    for (int m = 0; m < 10; m++) wp.w[m] = (const float*)d_in[wsrc[m]];
    wprep_kernel<<<2560, 256, 0, stream>>>(wp, wt);

    eadd_kernel<<<MD + MP, 256, 0, stream>>>(drug, prot, scale_d, scale_p, pe, e_d, e_p);

    auto W = [&](int slot) { return wt + (size_t)slot * 65536; };
    GCfg8 pc;
    pc.c[0] = { e_d, W(0), (const float*)d_in[5],  Qd,     145, 0 };
    pc.c[1] = { e_d, W(1), (const float*)d_in[13], Kd,     145, 0 };
    pc.c[2] = { e_d, W(2), (const float*)d_in[15], Vd,     145, 0 };
    pc.c[3] = { e_d, W(3), (const float*)d_in[26], gate_d, 145, 1 };
    pc.c[4] = { e_p, W(4), (const float*)d_in[7],  Kp,     500, 0 };
    pc.c[5] = { e_p, W(5), (const float*)d_in[9],  Vp,     500, 0 };
    pc.c[6] = { e_p, W(6), (const float*)d_in[11], Qp,     500, 0 };
    pc.c[7] = { e_p, W(7), (const float*)d_in[28], gate_p, 500, 1 };
    gemm_kernel<<<dim3(500, 4, 8), 256, 0, stream>>>(pc);

    attn_kernel<<<256, 512, 0, stream>>>(Qd, Kd, Vd, Kp, Vp, Qp,
                                         (const float*)d_in[20], ctxd, ctxp, cm);

    GCfg8 oc = pc;
    oc.c[0] = { ctxd, W(8), (const float*)d_in[17], Xd, 145, 0 };
    oc.c[1] = { ctxp, W(9), (const float*)d_in[19], Xp, 500, 0 };
    gemm_kernel<<<dim3(500, 4, 2), 256, 0, stream>>>(oc);

    combine_kernel<<<MD + MP, 256, 0, stream>>>(drug, prot, scale_d, scale_p, pe,
        Xd, Xp, gate_d, gate_p, cm,
        (const float*)d_in[21], (const float*)d_in[22],
        (const float*)d_in[23], (const float*)d_in[24],
        (float*)d_out);
}